// Round 6
// baseline (714.147 us; speedup 1.0000x reference)
//
#include <hip/hip_runtime.h>
#include <cstdint>
#include <cstddef>

#define C_DIM 768
#define N_DIM 16384

typedef __attribute__((ext_vector_type(4))) int i32x4;   // 16 i8 / 4 i32 accs

__device__ __forceinline__ void async_ld16(const void* g, void* l) {
    __builtin_amdgcn_global_load_lds(
        (__attribute__((address_space(1))) void*)g,
        (__attribute__((address_space(3))) void*)l,
        16, 0, 0);
}

// ---------------------------------------------------------------------------
// Per-column symmetric int8 quantization of the L2-normalized features,
// written transposed:  Q[i][c] = rint( F[c][i] * 127 / mx_i ),
// dequant scale  s[i] = mx_i / (127 * max(||col_i||, eps)).
// The norm cancels in the quant multiplier; sim = dotq * s_a[m] * s_b[n].
// blockIdx.y selects the input.
// ---------------------------------------------------------------------------
__global__ __launch_bounds__(256) void norm_q(const float* __restrict__ F0,
                                              signed char* __restrict__ Q0,
                                              float* __restrict__ S0,
                                              const float* __restrict__ F1,
                                              signed char* __restrict__ Q1,
                                              float* __restrict__ S1) {
    const float*  F = blockIdx.y ? F1 : F0;
    signed char*  Q = blockIdx.y ? Q1 : Q0;
    float*        S = blockIdx.y ? S1 : S0;
    const int i0 = blockIdx.x * 64;
    const int t  = threadIdx.x;
    const int tx = t & 63;
    const int ty = t >> 6;

    // ---- phase 1: per-column sumsq and max|.| ----
    float ss = 0.f, mx = 0.f;
    for (int c = ty; c < C_DIM; c += 4) {
        float v = F[(size_t)c * N_DIM + i0 + tx];
        ss += v * v;
        mx = fmaxf(mx, fabsf(v));
    }
    __shared__ float red_s[4][64];
    __shared__ float red_m[4][64];
    __shared__ float qscale[64];
    red_s[ty][tx] = ss;
    red_m[ty][tx] = mx;
    __syncthreads();
    if (t < 64) {
        float s = red_s[0][t] + red_s[1][t] + red_s[2][t] + red_s[3][t];
        float m = fmaxf(fmaxf(red_m[0][t], red_m[1][t]),
                        fmaxf(red_m[2][t], red_m[3][t]));
        float n = fmaxf(sqrtf(s), 1e-12f);
        qscale[t] = 127.0f / m;                 // quant multiplier (norm cancels)
        S[i0 + t] = m / (127.0f * n);           // dequant scale
    }
    __syncthreads();

    // ---- phase 2: transpose in 64x64 chunks (quant domain), pack i8 ----
    __shared__ float tile[64][65];
    const int i_l   = t >> 3;
    const int c_off = (t & 7) * 8;
    for (int c0 = 0; c0 < C_DIM; c0 += 64) {
        #pragma unroll
        for (int rr = 0; rr < 16; ++rr) {
            int c_l = rr * 4 + ty;
            tile[c_l][tx] = F[(size_t)(c0 + c_l) * N_DIM + i0 + tx] * qscale[tx];
        }
        __syncthreads();
        #pragma unroll
        for (int half = 0; half < 2; ++half) {
            int il = i_l + half * 32;
            unsigned lo = 0, hi = 0;
            #pragma unroll
            for (int j = 0; j < 4; ++j) {
                int q = __float2int_rn(tile[c_off + j][il]);
                lo |= (unsigned)(q & 0xff) << (8 * j);
            }
            #pragma unroll
            for (int j = 0; j < 4; ++j) {
                int q = __float2int_rn(tile[c_off + 4 + j][il]);
                hi |= (unsigned)(q & 0xff) << (8 * j);
            }
            uint2 u; u.x = lo; u.y = hi;
            *(uint2*)&Q[(size_t)(i0 + il) * C_DIM + c0 + c_off] = u;
        }
        __syncthreads();
    }
}

// ---------------------------------------------------------------------------
// Fused GEMM + row-max, int8 (mfma_i32_16x16x64_i8):  the round-4/5 verified
// structure (dbuf LDS one-barrier, XOR swizzle = 0 conflicts, XCD n-slices,
// 128x256 tile / 512 threads / 8 waves of 64x64) with BK=64 per stage:
//   - same 64-B LDS row, same 16B/lane fragments, same 4-reg acc (VGPR ~64)
//   - 12 K-iters instead of 24: bytes per FLOP halved (the measured
//     per-iter cost is bytes-proportional -> ~2x on the GEMM)
// Dequant in the epilogue: sim = acc * s_a[m] * s_b[n], both scales > 0 so
// the column-max commutes with scaling by s_a.
// ---------------------------------------------------------------------------
__global__ __launch_bounds__(512) void gemm_rowmax(const signed char* __restrict__ A,
                                                   const signed char* __restrict__ B,
                                                   const float* __restrict__ sA,
                                                   const float* __restrict__ sB,
                                                   unsigned* __restrict__ rowkey) {
    __shared__ __align__(16) signed char As[2][128 * 64];   // 16 KB
    __shared__ __align__(16) signed char Bs[2][256 * 64];   // 32 KB

    const int t    = threadIdx.x;
    const int lane = t & 63;
    const int w    = t >> 6;          // 0..7
    const int wm   = w >> 2;          // 0..1  (64-row half)
    const int wn   = w & 3;           // 0..3  (64-col quarter)

    // XCD-aware mapping: xcd owns an 8-tile n-slice; n fastest for A reuse.
    const int bid   = blockIdx.x;
    const int xcd   = bid & 7;
    const int local = bid >> 3;                     // 0..1023
    const int m0    = (local >> 3) * 128;
    const int n0    = (xcd * 8 + (local & 7)) * 256;

    i32x4 acc[4][4];
    #pragma unroll
    for (int i = 0; i < 4; ++i)
        #pragma unroll
        for (int j = 0; j < 4; ++j)
            acc[i][j] = (i32x4){0, 0, 0, 0};

    // staging: thread t -> row t>>2, phys 16B chunk t&3 at LDS byte t*16;
    // logical 16B k-chunk XOR-swizzled by row bits 1-2 (verified, 0 confl).
    const int kq = ((t & 3) ^ ((t >> 3) & 3)) * 16;      // i8 elements
    const signed char* ag  = A + (size_t)(m0 + (t >> 2)) * C_DIM + kq;
    const signed char* bg0 = B + (size_t)(n0 + (t >> 2)) * C_DIM + kq;
    const signed char* bg1 = bg0 + (size_t)128 * C_DIM;
    const int lda  = t * 16;                             // byte offsets in LDS
    const int ldb0 = t * 16, ldb1 = 128 * 64 + t * 16;

    // fragment reads: logical k-chunk x = lane>>4 lives at chunkpos
    // x ^ ((row>>1)&3); row = base + (lane&15), base % 16 == 0.
    const int qp    = ((lane >> 4) ^ ((lane >> 1) & 3)) * 16;   // bytes
    const int a_off = (wm * 64 + (lane & 15)) * 64 + qp;
    const int b_off = (wn * 64 + (lane & 15)) * 64 + qp;

    // prologue: stage k0=0 into buffer 0
    async_ld16(ag,  As[0] + lda);
    async_ld16(bg0, Bs[0] + ldb0);
    async_ld16(bg1, Bs[0] + ldb1);

    int buf = 0;
    for (int k0 = 0; k0 < C_DIM; k0 += 64) {
        __syncthreads();   // buf[k] staged; prior reads of buf^1 complete
        if (k0 + 64 < C_DIM) {
            const int kn = k0 + 64, nb = buf ^ 1;
            async_ld16(ag + kn,  As[nb] + lda);
            async_ld16(bg0 + kn, Bs[nb] + ldb0);
            async_ld16(bg1 + kn, Bs[nb] + ldb1);
        }

        const signed char* Ab = As[buf];
        const signed char* Bb = Bs[buf];
        i32x4 af[4], bfr[4];
        #pragma unroll
        for (int mt = 0; mt < 4; ++mt)
            af[mt] = *(const i32x4*)(Ab + a_off + mt * 16 * 64);
        #pragma unroll
        for (int nt = 0; nt < 4; ++nt)
            bfr[nt] = *(const i32x4*)(Bb + b_off + nt * 16 * 64);
        #pragma unroll
        for (int mt = 0; mt < 4; ++mt)
            #pragma unroll
            for (int nt = 0; nt < 4; ++nt)
                acc[mt][nt] = __builtin_amdgcn_mfma_i32_16x16x64_i8(
                    af[mt], bfr[nt], acc[mt][nt], 0, 0, 0);
        buf ^= 1;
    }

    // epilogue: dequant per column, max over this wave's 64 columns, then
    // scale by s_a and merge via atomicMax.
    // C/D layout: col = lane&15, row = (lane>>4)*4 + reg.
    float sb[4];
    #pragma unroll
    for (int nt = 0; nt < 4; ++nt)
        sb[nt] = sB[n0 + wn * 64 + nt * 16 + (lane & 15)];

    #pragma unroll
    for (int mt = 0; mt < 4; ++mt) {
        #pragma unroll
        for (int reg = 0; reg < 4; ++reg) {
            float v = fmaxf(fmaxf((float)acc[mt][0][reg] * sb[0],
                                  (float)acc[mt][1][reg] * sb[1]),
                            fmaxf((float)acc[mt][2][reg] * sb[2],
                                  (float)acc[mt][3][reg] * sb[3]));
            #pragma unroll
            for (int off = 1; off < 16; off <<= 1)
                v = fmaxf(v, __shfl_xor(v, off, 64));
            if ((lane & 15) == 0) {
                int m = m0 + wm * 64 + mt * 16 + (lane >> 4) * 4 + reg;
                v *= sA[m];
                unsigned u = __float_as_uint(v);
                u = (u & 0x80000000u) ? ~u : (u | 0x80000000u);  // order-preserving
                atomicMax(&rowkey[m], u);
            }
        }
    }
}

// ---------------------------------------------------------------------------
// Final: loss = 1 - mean(rowmax)
// ---------------------------------------------------------------------------
__global__ __launch_bounds__(1024) void finalize(const unsigned* __restrict__ rowkey,
                                                 float* __restrict__ out) {
    const int t = threadIdx.x;
    float s = 0.f;
    for (int i = t; i < N_DIM; i += 1024) {
        unsigned u = rowkey[i];
        float f = (u & 0x80000000u) ? __uint_as_float(u ^ 0x80000000u)
                                    : __uint_as_float(~u);
        s += f;
    }
    #pragma unroll
    for (int off = 32; off >= 1; off >>= 1)
        s += __shfl_down(s, off, 64);
    __shared__ float part[16];
    if ((t & 63) == 0) part[t >> 6] = s;
    __syncthreads();
    if (t == 0) {
        float tot = 0.f;
        #pragma unroll
        for (int i = 0; i < 16; ++i) tot += part[i];
        out[0] = 1.0f - tot * (1.0f / (float)N_DIM);
    }
}

extern "C" void kernel_launch(void* const* d_in, const int* in_sizes, int n_in,
                              void* d_out, int out_size, void* d_ws, size_t ws_size,
                              hipStream_t stream) {
    const float* F_r = (const float*)d_in[0];
    const float* F_s = (const float*)d_in[1];

    signed char* Rq = (signed char*)d_ws;                    // 16384 x 768 i8
    signed char* Sq = Rq + (size_t)N_DIM * C_DIM;            // 16384 x 768 i8
    float* sR       = (float*)(Sq + (size_t)N_DIM * C_DIM);  // 16384 f32
    float* sS       = sR + N_DIM;                            // 16384 f32
    unsigned* rowkey= (unsigned*)(sS + N_DIM);               // 16384 u32
    float* out      = (float*)d_out;

    hipLaunchKernelGGL(norm_q, dim3(N_DIM / 64, 2), dim3(256), 0, stream,
                       F_r, Rq, sR, F_s, Sq, sS);
    hipMemsetAsync(rowkey, 0, N_DIM * sizeof(unsigned), stream);
    hipLaunchKernelGGL(gemm_rowmax, dim3((N_DIM / 128) * (N_DIM / 256)), dim3(512),
                       0, stream, Rq, Sq, sR, sS, rowkey);
    hipLaunchKernelGGL(finalize, dim3(1), dim3(1024), 0, stream, rowkey, out);
}

// Round 8
// 713.712 us; speedup vs baseline: 1.0006x; 1.0006x over previous
//
#include <hip/hip_runtime.h>
#include <cstdint>
#include <cstddef>

#define C_DIM 768
#define N_DIM 16384

typedef __attribute__((ext_vector_type(4))) int i32x4;   // 16 i8 / 4 i32 accs

__device__ __forceinline__ void async_ld16(const void* g, void* l) {
    __builtin_amdgcn_global_load_lds(
        (__attribute__((address_space(1))) void*)g,
        (__attribute__((address_space(3))) void*)l,
        16, 0, 0);
}

// ---------------------------------------------------------------------------
// Per-column symmetric int8 quantization of the L2-normalized features,
// written transposed:  Q[i][c] = rint( F[c][i] * 127 / mx_i ),
// dequant scale  s[i] = mx_i / (127 * max(||col_i||, eps)).
// (verified round 6, absmax 0.0)
// ---------------------------------------------------------------------------
__global__ __launch_bounds__(256) void norm_q(const float* __restrict__ F0,
                                              signed char* __restrict__ Q0,
                                              float* __restrict__ S0,
                                              const float* __restrict__ F1,
                                              signed char* __restrict__ Q1,
                                              float* __restrict__ S1) {
    const float*  F = blockIdx.y ? F1 : F0;
    signed char*  Q = blockIdx.y ? Q1 : Q0;
    float*        S = blockIdx.y ? S1 : S0;
    const int i0 = blockIdx.x * 64;
    const int t  = threadIdx.x;
    const int tx = t & 63;
    const int ty = t >> 6;

    float ss = 0.f, mx = 0.f;
    for (int c = ty; c < C_DIM; c += 4) {
        float v = F[(size_t)c * N_DIM + i0 + tx];
        ss += v * v;
        mx = fmaxf(mx, fabsf(v));
    }
    __shared__ float red_s[4][64];
    __shared__ float red_m[4][64];
    __shared__ float qscale[64];
    red_s[ty][tx] = ss;
    red_m[ty][tx] = mx;
    __syncthreads();
    if (t < 64) {
        float s = red_s[0][t] + red_s[1][t] + red_s[2][t] + red_s[3][t];
        float m = fmaxf(fmaxf(red_m[0][t], red_m[1][t]),
                        fmaxf(red_m[2][t], red_m[3][t]));
        float n = fmaxf(sqrtf(s), 1e-12f);
        qscale[t] = 127.0f / m;
        S[i0 + t] = m / (127.0f * n);
    }
    __syncthreads();

    __shared__ float tile[64][65];
    const int i_l   = t >> 3;
    const int c_off = (t & 7) * 8;
    for (int c0 = 0; c0 < C_DIM; c0 += 64) {
        #pragma unroll
        for (int rr = 0; rr < 16; ++rr) {
            int c_l = rr * 4 + ty;
            tile[c_l][tx] = F[(size_t)(c0 + c_l) * N_DIM + i0 + tx] * qscale[tx];
        }
        __syncthreads();
        #pragma unroll
        for (int half = 0; half < 2; ++half) {
            int il = i_l + half * 32;
            unsigned lo = 0, hi = 0;
            #pragma unroll
            for (int j = 0; j < 4; ++j) {
                int q = __float2int_rn(tile[c_off + j][il]);
                lo |= (unsigned)(q & 0xff) << (8 * j);
            }
            #pragma unroll
            for (int j = 0; j < 4; ++j) {
                int q = __float2int_rn(tile[c_off + 4 + j][il]);
                hi |= (unsigned)(q & 0xff) << (8 * j);
            }
            uint2 u; u.x = lo; u.y = hi;
            *(uint2*)&Q[(size_t)(i0 + il) * C_DIM + c0 + c_off] = u;
        }
        __syncthreads();
    }
}

// ---------------------------------------------------------------------------
// BARRIER-FREE-hot-loop GEMM + row-max (int8, mfma_i32_16x16x64_i8).
//
// r4/r5/r6 lesson: one-barrier-per-K-iter costs a fixed latency quantum per
// barrier regardless of work between barriers (~540us across 3 tilings).
// So: no barriers in the hot loop.
//   - A m-tile (128x768 i8 = 96 KB) staged to LDS ONCE per block (single
//     barrier), XOR-swizzled per row -> conflict-free ds_read_b128.
//   - B read straight from global/L2 into VGPR fragments; compiler free to
//     pipeline these across the unrolled ks-body (barrier forbade this).
//   - Block = 128 rows x 8192-col half: 32 n-tiles of 256 (r7 bug: looped
//     128 -> read 4x past B/sB; fixed).
//   - Grid = 256 = CU count, 1 block/CU (96 KB LDS), no tail.  bid&1 = h
//     and XCD = bid&7, so each XCD reads only its own 6 MB B-half.
// ---------------------------------------------------------------------------
__global__ __launch_bounds__(512, 2) void gemm_rowmax(const signed char* __restrict__ A,
                                                      const signed char* __restrict__ B,
                                                      const float* __restrict__ sA,
                                                      const float* __restrict__ sB,
                                                      unsigned* __restrict__ rowkey) {
    __shared__ __align__(16) signed char As[128 * C_DIM];   // 96 KB

    const int t     = threadIdx.x;
    const int lane  = t & 63;
    const int w     = t >> 6;        // 0..7
    const int wm    = w >> 2;        // 0..1  (64-row half)
    const int wn    = w & 3;         // 0..3  (64-col quarter)
    const int row15 = lane & 15;
    const int kc    = lane >> 4;     // 0..3  (16B k-chunk within MFMA)
    const int x7    = lane & 7;

    const int bid = blockIdx.x;
    const int h   = bid & 1;             // n-half; xcd = bid&7 -> h fixed per XCD
    const int m0  = (bid >> 1) * 128;

    // ---- stage A once: slot s (16B) = row*48 + pc; holds logical chunk
    // lc = (pc&~7) | ((pc&7)^(row&7)).  Dest is linear (uniform base +
    // lane*16 per wave-issue) as global_load_lds requires. ----
    #pragma unroll
    for (int i = 0; i < 12; ++i) {
        int s   = i * 512 + t;
        int row = s / 48;                 // magic-mul
        int pc  = s - row * 48;
        int lc  = (pc & ~7) | ((pc & 7) ^ (row & 7));
        async_ld16(A + (size_t)(m0 + row) * C_DIM + lc * 16, As + s * 16);
    }
    __syncthreads();   // the ONLY barrier before the epilogue

    // B fragment base: B[n][k], n = h*8192 + ntile*256 + wn*64 + nt*16 + row15.
    const signed char* Bw = B + ((size_t)(h * 8192 + wn * 64 + row15)) * C_DIM
                              + kc * 16;
    const float* sBw = sB + h * 8192 + wn * 64 + row15;

    float runmax[4][4];
    #pragma unroll
    for (int mt = 0; mt < 4; ++mt)
        #pragma unroll
        for (int reg = 0; reg < 4; ++reg)
            runmax[mt][reg] = -1e30f;

    for (int ntile = 0; ntile < 32; ++ntile) {   // 32 * 256 = 8192-col half
        const signed char* Bt = Bw + (size_t)ntile * 256 * C_DIM;

        i32x4 acc[4][4];
        #pragma unroll
        for (int mt = 0; mt < 4; ++mt)
            #pragma unroll
            for (int nt = 0; nt < 4; ++nt)
                acc[mt][nt] = (i32x4){0, 0, 0, 0};

        #pragma unroll
        for (int ks = 0; ks < 12; ++ks) {
            i32x4 bfrag[4];
            #pragma unroll
            for (int nt = 0; nt < 4; ++nt)
                bfrag[nt] = *(const i32x4*)(Bt + (size_t)nt * 16 * C_DIM + ks * 64);

            // A logical chunk c = ks*4 + kc at phys (c&~7)|((c&7)^x7)
            const int c  = ks * 4 + kc;
            const int pc = (c & ~7) | ((c & 7) ^ x7);
            i32x4 afrag[4];
            #pragma unroll
            for (int mt = 0; mt < 4; ++mt)
                afrag[mt] = *(const i32x4*)(As + (wm * 64 + mt * 16 + row15) * C_DIM
                                               + pc * 16);

            #pragma unroll
            for (int mt = 0; mt < 4; ++mt)
                #pragma unroll
                for (int nt = 0; nt < 4; ++nt)
                    acc[mt][nt] = __builtin_amdgcn_mfma_i32_16x16x64_i8(
                        afrag[mt], bfrag[nt], acc[mt][nt], 0, 0, 0);
        }

        // dequant by per-col scale, fold into running max (scales > 0).
        float sb[4];
        #pragma unroll
        for (int nt = 0; nt < 4; ++nt)
            sb[nt] = sBw[ntile * 256 + nt * 16];

        #pragma unroll
        for (int mt = 0; mt < 4; ++mt)
            #pragma unroll
            for (int reg = 0; reg < 4; ++reg) {
                float v = fmaxf(fmaxf((float)acc[mt][0][reg] * sb[0],
                                      (float)acc[mt][1][reg] * sb[1]),
                                fmaxf((float)acc[mt][2][reg] * sb[2],
                                      (float)acc[mt][3][reg] * sb[3]));
                runmax[mt][reg] = fmaxf(runmax[mt][reg], v);
            }
    }

    // ---- epilogue: fold cols, scale by sA, order-preserving atomicMax.
    // C/D layout: col = lane&15, row = (lane>>4)*4 + reg. ----
    #pragma unroll
    for (int mt = 0; mt < 4; ++mt)
        #pragma unroll
        for (int reg = 0; reg < 4; ++reg) {
            float v = runmax[mt][reg];
            #pragma unroll
            for (int off = 1; off < 16; off <<= 1)
                v = fmaxf(v, __shfl_xor(v, off, 64));
            if (row15 == 0) {
                int m = m0 + wm * 64 + mt * 16 + kc * 4 + reg;
                v *= sA[m];
                unsigned u = __float_as_uint(v);
                u = (u & 0x80000000u) ? ~u : (u | 0x80000000u);
                atomicMax(&rowkey[m], u);
            }
        }
}

// ---------------------------------------------------------------------------
// Final: loss = 1 - mean(rowmax)
// ---------------------------------------------------------------------------
__global__ __launch_bounds__(1024) void finalize(const unsigned* __restrict__ rowkey,
                                                 float* __restrict__ out) {
    const int t = threadIdx.x;
    float s = 0.f;
    for (int i = t; i < N_DIM; i += 1024) {
        unsigned u = rowkey[i];
        float f = (u & 0x80000000u) ? __uint_as_float(u ^ 0x80000000u)
                                    : __uint_as_float(~u);
        s += f;
    }
    #pragma unroll
    for (int off = 32; off >= 1; off >>= 1)
        s += __shfl_down(s, off, 64);
    __shared__ float part[16];
    if ((t & 63) == 0) part[t >> 6] = s;
    __syncthreads();
    if (t == 0) {
        float tot = 0.f;
        #pragma unroll
        for (int i = 0; i < 16; ++i) tot += part[i];
        out[0] = 1.0f - tot * (1.0f / (float)N_DIM);
    }
}

extern "C" void kernel_launch(void* const* d_in, const int* in_sizes, int n_in,
                              void* d_out, int out_size, void* d_ws, size_t ws_size,
                              hipStream_t stream) {
    const float* F_r = (const float*)d_in[0];
    const float* F_s = (const float*)d_in[1];

    signed char* Rq = (signed char*)d_ws;                    // 16384 x 768 i8
    signed char* Sq = Rq + (size_t)N_DIM * C_DIM;            // 16384 x 768 i8
    float* sR       = (float*)(Sq + (size_t)N_DIM * C_DIM);  // 16384 f32
    float* sS       = sR + N_DIM;                            // 16384 f32
    unsigned* rowkey= (unsigned*)(sS + N_DIM);               // 16384 u32
    float* out      = (float*)d_out;

    hipLaunchKernelGGL(norm_q, dim3(N_DIM / 64, 2), dim3(256), 0, stream,
                       F_r, Rq, sR, F_s, Sq, sS);
    hipMemsetAsync(rowkey, 0, N_DIM * sizeof(unsigned), stream);
    hipLaunchKernelGGL(gemm_rowmax, dim3(256), dim3(512), 0, stream,
                       Rq, Sq, sR, sS, rowkey);
    hipLaunchKernelGGL(finalize, dim3(1), dim3(1024), 0, stream, rowkey, out);
}